// Round 16
// baseline (812.048 us; speedup 1.0000x reference)
//
#include <hip/hip_runtime.h>
#include <cstdio>
#include <cstddef>

// Problem dims
#define BB    256
#define TT    24
#define NFEAT 12
#define DIM   256
#define NH    8
#define DKH   32
#define FFD   512
#define SEQ_T 128
#define SEQ_F 153
#define NLAY  2

typedef unsigned short u16;
typedef u16   __attribute__((ext_vector_type(8))) u16x8;
typedef short __attribute__((ext_vector_type(8))) s16x8;
typedef float __attribute__((ext_vector_type(4))) f32x4;
typedef _Float16 __attribute__((ext_vector_type(2))) h16x2;

__device__ inline u16 f2bf(float f) {
    union { float f; unsigned u; } v; v.f = f;
    unsigned r = v.u + 0x7FFFu + ((v.u >> 16) & 1u);
    return (u16)(r >> 16);
}
__device__ inline float bf2f(u16 h) {
    union { unsigned u; float f; } v; v.u = ((unsigned)h) << 16;
    return v.f;
}
__device__ inline u16 f2h(float f) {
    union { _Float16 h; u16 u; } v; v.h = (_Float16)f; return v.u;
}
__device__ inline h16x2 u2h2(unsigned u) {
    union { unsigned u; h16x2 h; } v; v.u = u; return v.h;
}

// async global->LDS, 16B per lane. LDS dest is wave-uniform base + lane*16.
__device__ __forceinline__ void gload16(const u16* g, u16* l) {
    __builtin_amdgcn_global_load_lds(
        (const __attribute__((address_space(1))) unsigned int*)g,
        (__attribute__((address_space(3))) unsigned int*)l, 16, 0, 0);
}

// ---------------------------------------------------------------------------
// Prep: weight casts (float4) + PE + packed-fp16 Whh transpose + txt gather.
#define PER_ENC_CAST 1114112
__global__ __launch_bounds__(256) void prep_kernel(
    const float* __restrict__ t_in_W, const float* __restrict__ t_attn_W,
    const float* __restrict__ t_ff_W1, const float* __restrict__ t_ff_W2,
    const float* __restrict__ f_in_W, const float* __restrict__ f_attn_W,
    const float* __restrict__ f_ff_W1, const float* __restrict__ f_ff_W2,
    u16* __restrict__ wbf, float* __restrict__ pe,
    const float* __restrict__ Whh, u16* __restrict__ whhT2,
    const int* __restrict__ txts, const float* __restrict__ txt_emb,
    u16* __restrict__ gout)
{
    int blk = blockIdx.x;
    if (blk < 2176) {
        int i = (blk * 256 + threadIdx.x) * 4;
        int e = i >= PER_ENC_CAST;
        int off = i - e * PER_ENC_CAST;
        const float* src;
        if (off < 65536)       { src = (e ? f_in_W   : t_in_W)   + off; }
        else if (off < 589824) { src = (e ? f_attn_W : t_attn_W) + off - 65536; }
        else if (off < 851968) { src = (e ? f_ff_W1  : t_ff_W1)  + off - 589824; }
        else                   { src = (e ? f_ff_W2  : t_ff_W2)  + off - 851968; }
        float4 v = *(const float4*)src;
        ushort4 o;
        o.x = f2bf(v.x); o.y = f2bf(v.y); o.z = f2bf(v.z); o.w = f2bf(v.w);
        *(ushort4*)&wbf[i] = o;
    } else if (blk < 2329) {
        int s = blk - 2176, i = threadIdx.x;
        float e = (float)(2 * (i / 2)) * (1.0f / 256.0f);
        float freq = expf(-e * 9.210340371976184f);
        float ang = (float)s * freq;
        pe[s * 256 + i] = (i & 1) ? cosf(ang) : sinf(ang);
    } else if (blk < 3097) {
        // whhT2[(k>>1)*1536 + n*2 + (k&1)] = fp16(Whh[n][k])
        int n = blk - 2329, k = threadIdx.x;
        whhT2[(size_t)(k >> 1) * 1536 + n * 2 + (k & 1)] = f2h(Whh[(size_t)n * 256 + k]);
    } else {
        int r = blk - 3097, i = threadIdx.x;   // r in [0, BB*SEQ_T)
        gout[(size_t)r * 256 + i] = f2bf(txt_emb[(size_t)txts[r] * 256 + i]);
    }
}

// ---------------------------------------------------------------------------
// GRU-D scan: one block (768 threads) per batch; fdot2 fp16 matvec.
// First 64 weight pairs register-cached across all 24 steps (step-invariant).
// Writes h_t as bf16 DIRECTLY into the fusion sequence rows (b*153 + 1 + t).
__global__ __launch_bounds__(768) void grud_kernel(
    const float* __restrict__ x, const float* __restrict__ h0,
    const float* __restrict__ m, const float* __restrict__ dd,
    const float* __restrict__ x_m,
    const float* __restrict__ dec_w, const float* __restrict__ dec_b,
    const float* __restrict__ hd_W, const float* __restrict__ hd_b,
    const float* __restrict__ Wih, const float* __restrict__ bih,
    const u16* __restrict__ WhhT2, const float* __restrict__ bhh,
    u16* __restrict__ seq)
{
    int b = blockIdx.x;
    int tid = threadIdx.x;          // 0..767
    int gate = tid >> 8;            // 0=r 1=z 2=n
    int j = tid & 255;
    __shared__ float hcs[256], hdecs[256], r_s[256], z_s[256];
    __shared__ __align__(4) u16 hdecsh[256];   // fp16 copies for dot2
    __shared__ float dts[12], xcm[24];

    float wih[24];
#pragma unroll
    for (int i = 0; i < 24; i++) wih[i] = Wih[(size_t)tid * 24 + i];
    float bi_ = bih[tid], bh_ = bhh[tid];

    const u16* wcol = WhhT2 + tid * 2;
    // register-cache first 64 weight pairs (k = 0..127), step-invariant
    unsigned wreg[64];
#pragma unroll
    for (int k2 = 0; k2 < 64; k2++)
        wreg[k2] = *(const unsigned*)(wcol + (size_t)k2 * 1536);

    float hdw[12]; float hdb = 0.0f;
    if (tid < 256) {
#pragma unroll
        for (int i = 0; i < 12; i++) hdw[i] = hd_W[tid * 12 + i];
        hdb = hd_b[tid];
        hcs[tid] = h0[(size_t)b * 256 + tid];
    }
    __syncthreads();

    for (int t = 0; t < TT; t++) {
        if (tid < 12) {
            size_t idx = ((size_t)b * TT + t) * NFEAT + tid;
            float dv = dd[idx], xv = x[idx], mv = m[idx];
            float xd = expf(-fmaxf(dv * dec_w[tid] + dec_b[tid], 0.0f));
            dts[tid] = dv;
            xcm[tid] = mv * xv + (1.0f - mv) * xd * xv + (1.0f - mv) * (1.0f - xd) * x_m[tid];
            xcm[12 + tid] = mv;
        }
        __syncthreads();
        if (tid < 256) {
            float acc = hdb;
#pragma unroll
            for (int i = 0; i < 12; i++) acc += hdw[i] * dts[i];
            float hv = expf(-fmaxf(acc, 0.0f)) * hcs[tid];
            hdecs[tid] = hv;
            hdecsh[tid] = f2h(hv);
        }
        __syncthreads();
        float acc_i = bi_;
#pragma unroll
        for (int i = 0; i < 24; i++) acc_i += wih[i] * xcm[i];
        float a0 = bh_, a1 = 0.0f;
        // first half: weights from registers
#pragma unroll
        for (int k2 = 0; k2 < 64; k2 += 2) {
            unsigned hp0 = *(const unsigned*)&hdecsh[2 * k2];
            unsigned hp1 = *(const unsigned*)&hdecsh[2 * k2 + 2];
            a0 = __builtin_amdgcn_fdot2(u2h2(wreg[k2]),     u2h2(hp0), a0, false);
            a1 = __builtin_amdgcn_fdot2(u2h2(wreg[k2 + 1]), u2h2(hp1), a1, false);
        }
        // second half: weights from L2
#pragma unroll 8
        for (int k2 = 64; k2 < 128; k2 += 2) {
            unsigned wp0 = *(const unsigned*)(wcol + (size_t)k2 * 1536);
            unsigned wp1 = *(const unsigned*)(wcol + (size_t)(k2 + 1) * 1536);
            unsigned hp0 = *(const unsigned*)&hdecsh[2 * k2];
            unsigned hp1 = *(const unsigned*)&hdecsh[2 * k2 + 2];
            a0 = __builtin_amdgcn_fdot2(u2h2(wp0), u2h2(hp0), a0, false);
            a1 = __builtin_amdgcn_fdot2(u2h2(wp1), u2h2(hp1), a1, false);
        }
        float acc_h = a0 + a1;
        if (gate == 0) r_s[j] = 1.0f / (1.0f + expf(-(acc_i + acc_h)));
        else if (gate == 1) z_s[j] = 1.0f / (1.0f + expf(-(acc_i + acc_h)));
        __syncthreads();
        if (gate == 2) {
            float n = tanhf(acc_i + r_s[j] * acc_h);
            float hnew = (1.0f - z_s[j]) * n + z_s[j] * hdecs[j];
            hcs[j] = hnew;
            seq[((size_t)b * SEQ_F + 1 + t) * 256 + j] = f2bf(hnew);
        }
        __syncthreads();
    }
}

// ---------------------------------------------------------------------------
// Fill fusion-seq cls row only (emb rows by grud, text rows by text-final LN).
__global__ void build_cls_kernel(const float* __restrict__ fcls, u16* __restrict__ seq) {
    int b = blockIdx.x, i = threadIdx.x;
    seq[(size_t)b * SEQ_F * 256 + i] = f2bf(fcls[i]);
}

// ---------------------------------------------------------------------------
// Wide bf16 MFMA GEMM (qkv N=768, ff1 N=512): 128x256 tile, 512 threads =
// 8 waves (2 row x 4 col), BK=32, double-buffered LDS, global_load_lds.
template <int RELU>
__global__ __launch_bounds__(512) void gemm_wide_kernel(
    const u16* __restrict__ A, const u16* __restrict__ W,
    const float* __restrict__ bias, u16* __restrict__ Cout,
    int M, int N, int K)
{
    __shared__ u16 As[2][128 * 32];
    __shared__ u16 Bs[2][256 * 32];
    const int bm = blockIdx.y * 128, bn = blockIdx.x * 256;
    const int tid = threadIdx.x;
    const int w = tid >> 6, lane = tid & 63;
    const int wm = (w >> 2) * 64, wn = (w & 3) * 64;
    const int l15 = lane & 15, l16 = lane >> 4;
    const int srow = lane >> 2, scol = (lane & 3) * 8;
    f32x4 acc[4][4] = {};

    const u16* ga0 = A + (size_t)(bm + 16 * w + srow) * K + scol;
    const u16* gb0 = W + (size_t)(bn + 16 * w + srow) * K + scol;
    const u16* gb1 = W + (size_t)(bn + 128 + 16 * w + srow) * K + scol;

#define STAGE_W(buf, kk)                                      \
    do {                                                      \
        gload16(ga0 + (kk), &As[buf][16 * w * 32]);           \
        gload16(gb0 + (kk), &Bs[buf][16 * w * 32]);           \
        gload16(gb1 + (kk), &Bs[buf][(128 + 16 * w) * 32]);   \
    } while (0)

    STAGE_W(0, 0);
    __syncthreads();
    int cur = 0;
    for (int k0 = 0; k0 < K; k0 += 32) {
        if (k0 + 32 < K) STAGE_W(cur ^ 1, k0 + 32);
        s16x8 af[4], bfr[4];
#pragma unroll
        for (int i = 0; i < 4; i++)
            af[i] = *(const s16x8*)&As[cur][(wm + i * 16 + l15) * 32 + l16 * 8];
#pragma unroll
        for (int i = 0; i < 4; i++)
            bfr[i] = *(const s16x8*)&Bs[cur][(wn + i * 16 + l15) * 32 + l16 * 8];
#pragma unroll
        for (int mi = 0; mi < 4; mi++)
#pragma unroll
            for (int ni = 0; ni < 4; ni++)
                acc[mi][ni] = __builtin_amdgcn_mfma_f32_16x16x32_bf16(af[mi], bfr[ni], acc[mi][ni], 0, 0, 0);
        __syncthreads();
        cur ^= 1;
    }
#undef STAGE_W
#pragma unroll
    for (int mi = 0; mi < 4; mi++)
#pragma unroll
        for (int ni = 0; ni < 4; ni++) {
            int col = bn + wn + ni * 16 + l15;
            float bv = bias[col];
#pragma unroll
            for (int r = 0; r < 4; r++) {
                int row = bm + wm + mi * 16 + l16 * 4 + r;
                float v = acc[mi][ni][r] + bv;
                if (RELU) v = fmaxf(v, 0.0f);
                Cout[(size_t)row * N + col] = f2bf(v);
            }
        }
}

// ---------------------------------------------------------------------------
// Fused GEMM (N=256) + bias (+bf16 residual) + LayerNorm (+PE | *mask).
// 128x256 tile, 512 threads = 8 waves. Output row remap: orow = ob + bb*ostr + sr.
template <int ADDLN>
__global__ __launch_bounds__(512) void gemm_ln_kernel(
    const u16* __restrict__ A, const u16* __restrict__ W,
    const float* __restrict__ bias, const u16* __restrict__ res,
    const float* __restrict__ pe,
    const float* __restrict__ g, const float* __restrict__ b2,
    const int* __restrict__ lengths, int len_add, int S,
    u16* __restrict__ outbf, int ob, int ostr, int M, int K)
{
    __shared__ u16 As[2][128 * 32];
    __shared__ u16 Bs[2][256 * 32];
    __shared__ float2 red[4][128];
    __shared__ float2 red2[128];
    const int bm = blockIdx.x * 128;
    const int tid = threadIdx.x;
    const int w = tid >> 6, lane = tid & 63;
    const int wm = (w >> 2) * 64, wc = w & 3, wn = wc * 64;
    const int l15 = lane & 15, l16 = lane >> 4;
    const int srow = lane >> 2, scol = (lane & 3) * 8;
    f32x4 acc[4][4] = {};

    const u16* ga0 = A + (size_t)(bm + 16 * w + srow) * K + scol;
    const u16* gb0 = W + (size_t)(16 * w + srow) * K + scol;
    const u16* gb1 = W + (size_t)(128 + 16 * w + srow) * K + scol;

#define STAGE_L(buf, kk)                                      \
    do {                                                      \
        gload16(ga0 + (kk), &As[buf][16 * w * 32]);           \
        gload16(gb0 + (kk), &Bs[buf][16 * w * 32]);           \
        gload16(gb1 + (kk), &Bs[buf][(128 + 16 * w) * 32]);   \
    } while (0)

    STAGE_L(0, 0);
    __syncthreads();
    int cur = 0;
    for (int k0 = 0; k0 < K; k0 += 32) {
        if (k0 + 32 < K) STAGE_L(cur ^ 1, k0 + 32);
        s16x8 af[4], bfr[4];
#pragma unroll
        for (int i = 0; i < 4; i++)
            af[i] = *(const s16x8*)&As[cur][(wm + i * 16 + l15) * 32 + l16 * 8];
#pragma unroll
        for (int i = 0; i < 4; i++)
            bfr[i] = *(const s16x8*)&Bs[cur][(wn + i * 16 + l15) * 32 + l16 * 8];
#pragma unroll
        for (int mi = 0; mi < 4; mi++)
#pragma unroll
            for (int ni = 0; ni < 4; ni++)
                acc[mi][ni] = __builtin_amdgcn_mfma_f32_16x16x32_bf16(af[mi], bfr[ni], acc[mi][ni], 0, 0, 0);
        __syncthreads();
        cur ^= 1;
    }
#undef STAGE_L

    float bcol[4];
#pragma unroll
    for (int ni = 0; ni < 4; ni++) bcol[ni] = bias[wn + ni * 16 + l15];
#pragma unroll
    for (int mi = 0; mi < 4; mi++)
#pragma unroll
        for (int ni = 0; ni < 4; ni++)
#pragma unroll
            for (int r = 0; r < 4; r++) {
                float v = acc[mi][ni][r] + bcol[ni];
                if (ADDLN)
                    v += bf2f(res[(size_t)(bm + wm + mi * 16 + l16 * 4 + r) * 256 + wn + ni * 16 + l15]);
                acc[mi][ni][r] = v;
            }
#pragma unroll
    for (int mi = 0; mi < 4; mi++)
#pragma unroll
        for (int r = 0; r < 4; r++) {
            float s = 0.0f, q = 0.0f;
#pragma unroll
            for (int ni = 0; ni < 4; ni++) { float v = acc[mi][ni][r]; s += v; q += v * v; }
#pragma unroll
            for (int off = 1; off <= 8; off <<= 1) {
                s += __shfl_xor(s, off, 64);
                q += __shfl_xor(q, off, 64);
            }
            if (l15 == 0) {
                float2 p; p.x = s; p.y = q;
                red[wc][wm + mi * 16 + l16 * 4 + r] = p;
            }
        }
    __syncthreads();
    if (tid < 128) {
        float s = 0.0f, q = 0.0f;
#pragma unroll
        for (int c = 0; c < 4; c++) { float2 p = red[c][tid]; s += p.x; q += p.y; }
        float mean = s * (1.0f / 256.0f);
        float var = q * (1.0f / 256.0f) - mean * mean;
        float2 o; o.x = mean; o.y = rsqrtf(var + 1e-5f);
        red2[tid] = o;
    }
    __syncthreads();
#pragma unroll
    for (int mi = 0; mi < 4; mi++)
#pragma unroll
        for (int r = 0; r < 4; r++) {
            int lrow = wm + mi * 16 + l16 * 4 + r;
            int grow = bm + lrow;
            float2 mr = red2[lrow];
            int bb = grow / S, sr = grow - bb * S;
            float mask = 1.0f;
            if (ADDLN) mask = (sr < lengths[bb] + len_add) ? 1.0f : 0.0f;
            size_t orow = (size_t)ob + (size_t)bb * ostr + sr;
#pragma unroll
            for (int ni = 0; ni < 4; ni++) {
                int col = wn + ni * 16 + l15;
                float o = (acc[mi][ni][r] - mr.x) * mr.y * g[col] + b2[col];
                if (ADDLN) o *= mask;
                else       o += pe[sr * 256 + col];
                outbf[orow * 256 + col] = f2bf(o);
            }
        }
}

// ---------------------------------------------------------------------------
// MFMA flash attention. One block per (b,h), 256 threads (4 waves).
// q-tiles fully beyond len skipped: rows >= len are LN-masked to 0 downstream;
// stale ctx values are finite so LN stays finite.
__global__ __launch_bounds__(256) void attn_mfma_kernel(
    const u16* __restrict__ qkv, u16* __restrict__ ctx,
    const int* __restrict__ lengths, int len_add, int S)
{
    __shared__ u16 K_lds[160][40];
    __shared__ u16 Vt_lds[32][176];
    __shared__ u16 P_lds[4][16][48];

    const int bh = blockIdx.x;
    const int b = bh >> 3, h = bh & 7;
    const int len = lengths[b] + len_add;
    const int tid = threadIdx.x;
    const int w = tid >> 6;
    const int lane = tid & 63;
    const int l15 = lane & 15, l16 = lane >> 4;
    const int SR = (S + 31) & ~31;   // staged rows (128 text, 160 fusion)

    const u16* kbase = qkv + ((size_t)b * S) * 768 + 256 + h * 32;
    const u16* vbase = kbase + 256;
    for (int chunk = tid; chunk < SR * 4; chunk += 256) {
        int s = chunk >> 2, d8 = (chunk & 3) * 8;
        u16x8 kv = {}; u16x8 vv = {};
        if (s < S) {
            kv = *(const u16x8*)(kbase + (size_t)s * 768 + d8);
            vv = *(const u16x8*)(vbase + (size_t)s * 768 + d8);
        }
        *(u16x8*)&K_lds[s][d8] = kv;
#pragma unroll
        for (int j = 0; j < 8; j++) Vt_lds[d8 + j][s] = vv[j];
    }
    __syncthreads();

    const f32x4 zero4 = {0.0f, 0.0f, 0.0f, 0.0f};
    const float SCALE = 0.17677669529663687f;

    for (int q0 = w * 16; q0 < len; q0 += 64) {
        const int qr = min(q0 + l15, S - 1);
        s16x8 qf = *(const s16x8*)(qkv + ((size_t)(b * S + qr)) * 768 + h * 32 + l16 * 8);
        f32x4 o0 = zero4, o1 = zero4;
        float mreg = -1e30f, lreg = 0.0f;

        for (int k0 = 0; k0 < len; k0 += 32) {
            s16x8 kf0 = *(const s16x8*)&K_lds[k0 + l15][l16 * 8];
            s16x8 kf1 = *(const s16x8*)&K_lds[k0 + 16 + l15][l16 * 8];
            __builtin_amdgcn_s_setprio(1);
            f32x4 c0 = __builtin_amdgcn_mfma_f32_16x16x32_bf16(kf0, qf, zero4, 0, 0, 0);
            f32x4 c1 = __builtin_amdgcn_mfma_f32_16x16x32_bf16(kf1, qf, zero4, 0, 0, 0);
            __builtin_amdgcn_s_setprio(0);
            float sc[8];
#pragma unroll
            for (int r = 0; r < 4; r++) {
                int key0 = k0 + l16 * 4 + r;
                sc[r]     = (key0 < len)      ? c0[r] * SCALE : -1e30f;
                sc[4 + r] = (key0 + 16 < len) ? c1[r] * SCALE : -1e30f;
            }
            float tmax = sc[0];
#pragma unroll
            for (int i = 1; i < 8; i++) tmax = fmaxf(tmax, sc[i]);
            tmax = fmaxf(tmax, __shfl_xor(tmax, 16, 64));
            tmax = fmaxf(tmax, __shfl_xor(tmax, 32, 64));
            float mnew = fmaxf(mreg, tmax);
            float rescale = expf(mreg - mnew);
            float psum = 0.0f;
            u16 pb[8];
#pragma unroll
            for (int i = 0; i < 8; i++) {
                float p = expf(sc[i] - mnew);
                psum += p;
                pb[i] = f2bf(p);
            }
            psum += __shfl_xor(psum, 16, 64);
            psum += __shfl_xor(psum, 32, 64);
            lreg = lreg * rescale + psum;
            mreg = mnew;
#pragma unroll
            for (int i = 0; i < 4; i++) { o0[i] *= rescale; o1[i] *= rescale; }
#pragma unroll
            for (int r = 0; r < 4; r++) {
                P_lds[w][l15][l16 * 4 + r]      = pb[r];
                P_lds[w][l15][16 + l16 * 4 + r] = pb[4 + r];
            }
            s16x8 pf  = *(const s16x8*)&P_lds[w][l15][l16 * 8];
            s16x8 vf0 = *(const s16x8*)&Vt_lds[l15][k0 + l16 * 8];
            s16x8 vf1 = *(const s16x8*)&Vt_lds[16 + l15][k0 + l16 * 8];
            __builtin_amdgcn_s_setprio(1);
            o0 = __builtin_amdgcn_mfma_f32_16x16x32_bf16(vf0, pf, o0, 0, 0, 0);
            o1 = __builtin_amdgcn_mfma_f32_16x16x32_bf16(vf1, pf, o1, 0, 0, 0);
            __builtin_amdgcn_s_setprio(0);
        }

        float inv = 1.0f / lreg;
        int qg = q0 + l15;
        if (qg < S) {
            size_t ob = ((size_t)(b * S + qg)) * 256 + h * 32;
#pragma unroll
            for (int r = 0; r < 4; r++) {
                ctx[ob + l16 * 4 + r]      = f2bf(o0[r] * inv);
                ctx[ob + 16 + l16 * 4 + r] = f2bf(o1[r] * inv);
            }
        }
    }
}

// ---------------------------------------------------------------------------
__global__ __launch_bounds__(64) void classifier_kernel(
    const u16* __restrict__ encFb, const float* __restrict__ age, const float* __restrict__ gen,
    const float* __restrict__ fc1_W, const float* __restrict__ fc1_b,
    const float* __restrict__ bn_g, const float* __restrict__ bn_b,
    const float* __restrict__ fc2_W, const float* __restrict__ fc2_b,
    float* __restrict__ outp)
{
    int k = blockIdx.x, b = blockIdx.y, t = threadIdx.x;
    const u16* cls = encFb + (size_t)b * SEQ_F * 256;
    const float* wrow = fc1_W + ((size_t)k * 64 + t) * 258;
    float acc = fc1_b[k * 64 + t];
    for (int d2 = 0; d2 < 256; d2++) acc += bf2f(cls[d2]) * wrow[d2];
    acc += age[b] * wrow[256] + gen[b] * wrow[257];
    const float RSQ = 0.99999500003749980e0f;
    acc = acc * RSQ * bn_g[k * 64 + t] + bn_b[k * 64 + t];
    acc = fmaxf(acc, 0.0f);
    float p = acc * fc2_W[k * 64 + t];
#pragma unroll
    for (int o = 32; o >= 1; o >>= 1) p += __shfl_xor(p, o, 64);
    if (t == 0) outp[k * 256 + b] = 1.0f / (1.0f + expf(-(p + fc2_b[k])));
}

// ---------------------------------------------------------------------------
struct WB { const u16 *inW, *attnW, *ff1W, *ff2W; };

static void run_encoder(u16* enc_bf, const u16* a_in, u16* ctx_buf, u16* scr_b,
                        const WB& wb, const float* pe, int S,
                        const float* in_b, const float* attn_b,
                        const float* ff_b1, const float* ff_b2,
                        const float* ln_g, const float* ln_b,
                        const int* lengths, int len_add,
                        u16* fout, int fbase, int fstr, hipStream_t stream)
{
    int M = BB * S;
    int MB = M / 128;
    dim3 g512(512 / 256, MB), g768(768 / 256, MB);
    gemm_ln_kernel<0><<<MB, 512, 0, stream>>>(a_in, wb.inW, in_b, nullptr, pe,
                                              ln_g, ln_b, lengths, len_add, S,
                                              enc_bf, 0, S, M, 256);
    for (int l = 0; l < NLAY; l++) {
        const u16* wqkv = wb.attnW + (size_t)l * 4 * 65536;
        const u16* wout = wb.attnW + ((size_t)l * 4 + 3) * 65536;
        const float* bqkv = attn_b + (size_t)l * 4 * 256;
        const float* bout = attn_b + ((size_t)l * 4 + 3) * 256;
        gemm_wide_kernel<0><<<g768, 512, 0, stream>>>(enc_bf, wqkv, bqkv, scr_b, M, 768, 256);
        attn_mfma_kernel<<<BB * NH, 256, 0, stream>>>(scr_b, ctx_buf, lengths, len_add, S);
        gemm_ln_kernel<1><<<MB, 512, 0, stream>>>(ctx_buf, wout, bout, enc_bf, nullptr,
                                                  ln_g + (1 + 2 * l) * 256, ln_b + (1 + 2 * l) * 256,
                                                  lengths, len_add, S, enc_bf, 0, S, M, 256);
        gemm_wide_kernel<1><<<g512, 512, 0, stream>>>(enc_bf, wb.ff1W + (size_t)l * 512 * 256,
                                                      ff_b1 + l * 512, scr_b, M, 512, 256);
        // final sublayer may redirect its output (fusion-seq write-through)
        u16* ob = (l == NLAY - 1) ? fout : enc_bf;
        int obase = (l == NLAY - 1) ? fbase : 0;
        int ostr  = (l == NLAY - 1) ? fstr : S;
        gemm_ln_kernel<1><<<MB, 512, 0, stream>>>(scr_b, wb.ff2W + (size_t)l * 256 * 512,
                                                  ff_b2 + l * 256, enc_bf, nullptr,
                                                  ln_g + (2 + 2 * l) * 256, ln_b + (2 + 2 * l) * 256,
                                                  lengths, len_add, S, ob, obase, ostr, M, 512);
    }
}

// ---------------------------------------------------------------------------
extern "C" void kernel_launch(void* const* d_in, const int* in_sizes, int n_in,
                              void* d_out, int out_size, void* d_ws, size_t ws_size,
                              hipStream_t stream)
{
    const float* x        = (const float*)d_in[0];
    const float* h0       = (const float*)d_in[1];
    const float* m        = (const float*)d_in[2];
    const float* dd       = (const float*)d_in[3];
    const float* x_m      = (const float*)d_in[4];
    const float* age      = (const float*)d_in[5];
    const float* gen      = (const float*)d_in[6];
    const int*   txts     = (const int*)d_in[8];
    const int*   txt_len  = (const int*)d_in[9];
    const float* dec_w    = (const float*)d_in[10];
    const float* dec_b    = (const float*)d_in[11];
    const float* hd_W     = (const float*)d_in[12];
    const float* hd_b     = (const float*)d_in[13];
    const float* gru_Wih  = (const float*)d_in[14];
    const float* gru_Whh  = (const float*)d_in[15];
    const float* gru_bih  = (const float*)d_in[16];
    const float* gru_bhh  = (const float*)d_in[17];
    const float* txt_emb  = (const float*)d_in[18];
    const float* t_in_W   = (const float*)d_in[19];
    const float* t_in_b   = (const float*)d_in[20];
    const float* t_attn_W = (const float*)d_in[21];
    const float* t_attn_b = (const float*)d_in[22];
    const float* t_ff_W1  = (const float*)d_in[23];
    const float* t_ff_b1  = (const float*)d_in[24];
    const float* t_ff_W2  = (const float*)d_in[25];
    const float* t_ff_b2  = (const float*)d_in[26];
    const float* t_ln_g   = (const float*)d_in[27];
    const float* t_ln_b   = (const float*)d_in[28];
    const float* f_in_W   = (const float*)d_in[29];
    const float* f_in_b   = (const float*)d_in[30];
    const float* f_attn_W = (const float*)d_in[31];
    const float* f_attn_b = (const float*)d_in[32];
    const float* f_ff_W1  = (const float*)d_in[33];
    const float* f_ff_b1  = (const float*)d_in[34];
    const float* f_ff_W2  = (const float*)d_in[35];
    const float* f_ff_b2  = (const float*)d_in[36];
    const float* f_ln_g   = (const float*)d_in[37];
    const float* f_ln_b   = (const float*)d_in[38];
    const float* f_cls    = (const float*)d_in[39];
    const float* fc1_W    = (const float*)d_in[40];
    const float* fc1_b    = (const float*)d_in[41];
    const float* bn_g     = (const float*)d_in[42];
    const float* bn_b     = (const float*)d_in[43];
    const float* fc2_W    = (const float*)d_in[44];
    const float* fc2_b    = (const float*)d_in[45];
    float* outp = (float*)d_out;

    // Workspace layout (float units; bf16 regions use half)
    const size_t O_PE    = 0;                        // 40960
    const size_t O_WHHT  = 40960;                    // whhT2 fp16 (98304 u16)
    const size_t O_ENCT  = 1810432;                  // encTb (8388608 u16) + text ctx (8388608 u16)
    const size_t O_ENCF  = 10199040;                 // encF bf16
    const size_t O_SCR   = 20226048;                 // gather-in / qkv/ff1 bf16
    const size_t O_ACTX  = 35266560;                 // fusion seq / fusion ctx
    const size_t O_WBF   = 50307072;                 // weights bf16
    const size_t TOTALF  = 51421184;                 // ~205.7 MB

    if (ws_size < TOTALF * sizeof(float)) {
        fprintf(stderr, "kernel_launch: ws_size %zu < required %zu bytes\n",
                ws_size, TOTALF * sizeof(float));
        return;
    }
    float* ws    = (float*)d_ws;
    float* pe    = ws + O_PE;
    u16*   whhT2 = (u16*)(ws + O_WHHT);
    u16*   encTb = (u16*)(ws + O_ENCT);
    u16*   ctxT  = encTb + (size_t)BB * SEQ_T * 256;   // back half of encT region
    u16*   encFb = (u16*)(ws + O_ENCF);
    u16*   scr_b = (u16*)(ws + O_SCR);
    u16*   actx_b= (u16*)(ws + O_ACTX);
    u16*   wbf   = (u16*)(ws + O_WBF);

    const size_t PER_ENC = PER_ENC_CAST;
    WB wbT = { wbf + 0,       wbf + 65536,           wbf + 589824,           wbf + 851968 };
    WB wbF = { wbf + PER_ENC, wbf + PER_ENC + 65536, wbf + PER_ENC + 589824, wbf + PER_ENC + 851968 };

    // Prep: weight casts + PE + packed fp16 Whh + txt gather (-> scr_b)
    prep_kernel<<<3097 + BB * SEQ_T, 256, 0, stream>>>(
        t_in_W, t_attn_W, t_ff_W1, t_ff_W2,
        f_in_W, f_attn_W, f_ff_W1, f_ff_W2,
        wbf, pe, gru_Whh, whhT2, txts, txt_emb, scr_b);

    // GRU-D scan -> bf16 emb rows written directly into fusion seq (actx_b)
    grud_kernel<<<BB, 768, 0, stream>>>(x, h0, m, dd, x_m, dec_w, dec_b, hd_W, hd_b,
                                        gru_Wih, gru_bih, whhT2, gru_bhh, actx_b);
    build_cls_kernel<<<BB, 256, 0, stream>>>(f_cls, actx_b);

    // Text encoder: A = gather (scr_b), ctx = ctxT (so fusion seq stays intact);
    // final ff2-LN writes DIRECTLY into fusion seq rows (b*153+25+s)
    run_encoder(encTb, scr_b, ctxT, scr_b, wbT, pe, SEQ_T,
                t_in_b, t_attn_b, t_ff_b1, t_ff_b2, t_ln_g, t_ln_b, txt_len, 0,
                actx_b, 25, SEQ_F, stream);

    // Fusion encoder: A = seq (actx_b), ctx = actx_b (seq dead after in-proj)
    run_encoder(encFb, actx_b, actx_b, scr_b, wbF, pe, SEQ_F,
                f_in_b, f_attn_b, f_ff_b1, f_ff_b2, f_ln_g, f_ln_b, txt_len, 25,
                encFb, 0, SEQ_F, stream);

    classifier_kernel<<<dim3(12, BB), 64, 0, stream>>>(encFb, age, gen, fc1_W, fc1_b,
                                                       bn_g, bn_b, fc2_W, fc2_b, outp);
}

// Round 17
// 786.594 us; speedup vs baseline: 1.0324x; 1.0324x over previous
//
#include <hip/hip_runtime.h>
#include <cstdio>
#include <cstddef>

// Problem dims
#define BB    256
#define TT    24
#define NFEAT 12
#define DIM   256
#define NH    8
#define DKH   32
#define FFD   512
#define SEQ_T 128
#define SEQ_F 153
#define NLAY  2

typedef unsigned short u16;
typedef u16   __attribute__((ext_vector_type(8))) u16x8;
typedef short __attribute__((ext_vector_type(8))) s16x8;
typedef float __attribute__((ext_vector_type(4))) f32x4;
typedef _Float16 __attribute__((ext_vector_type(2))) h16x2;

__device__ inline u16 f2bf(float f) {
    union { float f; unsigned u; } v; v.f = f;
    unsigned r = v.u + 0x7FFFu + ((v.u >> 16) & 1u);
    return (u16)(r >> 16);
}
__device__ inline float bf2f(u16 h) {
    union { unsigned u; float f; } v; v.u = ((unsigned)h) << 16;
    return v.f;
}
__device__ inline u16 f2h(float f) {
    union { _Float16 h; u16 u; } v; v.h = (_Float16)f; return v.u;
}
__device__ inline h16x2 u2h2(unsigned u) {
    union { unsigned u; h16x2 h; } v; v.u = u; return v.h;
}

// async global->LDS, 16B per lane. LDS dest is wave-uniform base + lane*16.
__device__ __forceinline__ void gload16(const u16* g, u16* l) {
    __builtin_amdgcn_global_load_lds(
        (const __attribute__((address_space(1))) unsigned int*)g,
        (__attribute__((address_space(3))) unsigned int*)l, 16, 0, 0);
}

// ---------------------------------------------------------------------------
// Prep: weight casts (float4) + PE + packed-fp16 Whh transpose + txt gather.
#define PER_ENC_CAST 1114112
__global__ __launch_bounds__(256) void prep_kernel(
    const float* __restrict__ t_in_W, const float* __restrict__ t_attn_W,
    const float* __restrict__ t_ff_W1, const float* __restrict__ t_ff_W2,
    const float* __restrict__ f_in_W, const float* __restrict__ f_attn_W,
    const float* __restrict__ f_ff_W1, const float* __restrict__ f_ff_W2,
    u16* __restrict__ wbf, float* __restrict__ pe,
    const float* __restrict__ Whh, u16* __restrict__ whhT2,
    const int* __restrict__ txts, const float* __restrict__ txt_emb,
    u16* __restrict__ gout)
{
    int blk = blockIdx.x;
    if (blk < 2176) {
        int i = (blk * 256 + threadIdx.x) * 4;
        int e = i >= PER_ENC_CAST;
        int off = i - e * PER_ENC_CAST;
        const float* src;
        if (off < 65536)       { src = (e ? f_in_W   : t_in_W)   + off; }
        else if (off < 589824) { src = (e ? f_attn_W : t_attn_W) + off - 65536; }
        else if (off < 851968) { src = (e ? f_ff_W1  : t_ff_W1)  + off - 589824; }
        else                   { src = (e ? f_ff_W2  : t_ff_W2)  + off - 851968; }
        float4 v = *(const float4*)src;
        ushort4 o;
        o.x = f2bf(v.x); o.y = f2bf(v.y); o.z = f2bf(v.z); o.w = f2bf(v.w);
        *(ushort4*)&wbf[i] = o;
    } else if (blk < 2329) {
        int s = blk - 2176, i = threadIdx.x;
        float e = (float)(2 * (i / 2)) * (1.0f / 256.0f);
        float freq = expf(-e * 9.210340371976184f);
        float ang = (float)s * freq;
        pe[s * 256 + i] = (i & 1) ? cosf(ang) : sinf(ang);
    } else if (blk < 3097) {
        // whhT2[(k>>1)*1536 + n*2 + (k&1)] = fp16(Whh[n][k])
        int n = blk - 2329, k = threadIdx.x;
        whhT2[(size_t)(k >> 1) * 1536 + n * 2 + (k & 1)] = f2h(Whh[(size_t)n * 256 + k]);
    } else {
        int r = blk - 3097, i = threadIdx.x;   // r in [0, BB*SEQ_T)
        gout[(size_t)r * 256 + i] = f2bf(txt_emb[(size_t)txts[r] * 256 + i]);
    }
}

// ---------------------------------------------------------------------------
// GRU-D scan: one block (768 threads) per batch; fdot2 fp16 matvec
// (R14/R15-measured 120us form; R16's register-cache variant regressed).
// Writes h_t as bf16 DIRECTLY into the fusion sequence rows (b*153 + 1 + t).
__global__ __launch_bounds__(768) void grud_kernel(
    const float* __restrict__ x, const float* __restrict__ h0,
    const float* __restrict__ m, const float* __restrict__ dd,
    const float* __restrict__ x_m,
    const float* __restrict__ dec_w, const float* __restrict__ dec_b,
    const float* __restrict__ hd_W, const float* __restrict__ hd_b,
    const float* __restrict__ Wih, const float* __restrict__ bih,
    const u16* __restrict__ WhhT2, const float* __restrict__ bhh,
    u16* __restrict__ seq)
{
    int b = blockIdx.x;
    int tid = threadIdx.x;          // 0..767
    int gate = tid >> 8;            // 0=r 1=z 2=n
    int j = tid & 255;
    __shared__ float hcs[256], hdecs[256], r_s[256], z_s[256];
    __shared__ __align__(4) u16 hdecsh[256];   // fp16 copies for dot2
    __shared__ float dts[12], xcm[24];

    float wih[24];
#pragma unroll
    for (int i = 0; i < 24; i++) wih[i] = Wih[(size_t)tid * 24 + i];
    float bi_ = bih[tid], bh_ = bhh[tid];

    float hdw[12]; float hdb = 0.0f;
    if (tid < 256) {
#pragma unroll
        for (int i = 0; i < 12; i++) hdw[i] = hd_W[tid * 12 + i];
        hdb = hd_b[tid];
        hcs[tid] = h0[(size_t)b * 256 + tid];
    }
    __syncthreads();

    const u16* wcol = WhhT2 + tid * 2;
    for (int t = 0; t < TT; t++) {
        if (tid < 12) {
            size_t idx = ((size_t)b * TT + t) * NFEAT + tid;
            float dv = dd[idx], xv = x[idx], mv = m[idx];
            float xd = expf(-fmaxf(dv * dec_w[tid] + dec_b[tid], 0.0f));
            dts[tid] = dv;
            xcm[tid] = mv * xv + (1.0f - mv) * xd * xv + (1.0f - mv) * (1.0f - xd) * x_m[tid];
            xcm[12 + tid] = mv;
        }
        __syncthreads();
        if (tid < 256) {
            float acc = hdb;
#pragma unroll
            for (int i = 0; i < 12; i++) acc += hdw[i] * dts[i];
            float hv = expf(-fmaxf(acc, 0.0f)) * hcs[tid];
            hdecs[tid] = hv;
            hdecsh[tid] = f2h(hv);
        }
        __syncthreads();
        float acc_i = bi_;
#pragma unroll
        for (int i = 0; i < 24; i++) acc_i += wih[i] * xcm[i];
        float a0 = bh_, a1 = 0.0f;
#pragma unroll 8
        for (int k2 = 0; k2 < 128; k2 += 2) {
            unsigned wp0 = *(const unsigned*)(wcol + (size_t)k2 * 1536);
            unsigned wp1 = *(const unsigned*)(wcol + (size_t)(k2 + 1) * 1536);
            unsigned hp0 = *(const unsigned*)&hdecsh[2 * k2];
            unsigned hp1 = *(const unsigned*)&hdecsh[2 * k2 + 2];
            a0 = __builtin_amdgcn_fdot2(u2h2(wp0), u2h2(hp0), a0, false);
            a1 = __builtin_amdgcn_fdot2(u2h2(wp1), u2h2(hp1), a1, false);
        }
        float acc_h = a0 + a1;
        if (gate == 0) r_s[j] = 1.0f / (1.0f + expf(-(acc_i + acc_h)));
        else if (gate == 1) z_s[j] = 1.0f / (1.0f + expf(-(acc_i + acc_h)));
        __syncthreads();
        if (gate == 2) {
            float n = tanhf(acc_i + r_s[j] * acc_h);
            float hnew = (1.0f - z_s[j]) * n + z_s[j] * hdecs[j];
            hcs[j] = hnew;
            seq[((size_t)b * SEQ_F + 1 + t) * 256 + j] = f2bf(hnew);
        }
        __syncthreads();
    }
}

// ---------------------------------------------------------------------------
// Fill fusion-seq cls row only (emb rows by grud, text rows by text-final LN).
__global__ void build_cls_kernel(const float* __restrict__ fcls, u16* __restrict__ seq) {
    int b = blockIdx.x, i = threadIdx.x;
    seq[(size_t)b * SEQ_F * 256 + i] = f2bf(fcls[i]);
}

// ---------------------------------------------------------------------------
// Wide bf16 MFMA GEMM (qkv N=768, ff1 N=512): 128x256 tile, 512 threads =
// 8 waves (2 row x 4 col), BK=32, double-buffered LDS, global_load_lds.
template <int RELU>
__global__ __launch_bounds__(512) void gemm_wide_kernel(
    const u16* __restrict__ A, const u16* __restrict__ W,
    const float* __restrict__ bias, u16* __restrict__ Cout,
    int M, int N, int K)
{
    __shared__ u16 As[2][128 * 32];
    __shared__ u16 Bs[2][256 * 32];
    const int bm = blockIdx.y * 128, bn = blockIdx.x * 256;
    const int tid = threadIdx.x;
    const int w = tid >> 6, lane = tid & 63;
    const int wm = (w >> 2) * 64, wn = (w & 3) * 64;
    const int l15 = lane & 15, l16 = lane >> 4;
    const int srow = lane >> 2, scol = (lane & 3) * 8;
    f32x4 acc[4][4] = {};

    const u16* ga0 = A + (size_t)(bm + 16 * w + srow) * K + scol;
    const u16* gb0 = W + (size_t)(bn + 16 * w + srow) * K + scol;
    const u16* gb1 = W + (size_t)(bn + 128 + 16 * w + srow) * K + scol;

#define STAGE_W(buf, kk)                                      \
    do {                                                      \
        gload16(ga0 + (kk), &As[buf][16 * w * 32]);           \
        gload16(gb0 + (kk), &Bs[buf][16 * w * 32]);           \
        gload16(gb1 + (kk), &Bs[buf][(128 + 16 * w) * 32]);   \
    } while (0)

    STAGE_W(0, 0);
    __syncthreads();
    int cur = 0;
    for (int k0 = 0; k0 < K; k0 += 32) {
        if (k0 + 32 < K) STAGE_W(cur ^ 1, k0 + 32);
        s16x8 af[4], bfr[4];
#pragma unroll
        for (int i = 0; i < 4; i++)
            af[i] = *(const s16x8*)&As[cur][(wm + i * 16 + l15) * 32 + l16 * 8];
#pragma unroll
        for (int i = 0; i < 4; i++)
            bfr[i] = *(const s16x8*)&Bs[cur][(wn + i * 16 + l15) * 32 + l16 * 8];
#pragma unroll
        for (int mi = 0; mi < 4; mi++)
#pragma unroll
            for (int ni = 0; ni < 4; ni++)
                acc[mi][ni] = __builtin_amdgcn_mfma_f32_16x16x32_bf16(af[mi], bfr[ni], acc[mi][ni], 0, 0, 0);
        __syncthreads();
        cur ^= 1;
    }
#undef STAGE_W
#pragma unroll
    for (int mi = 0; mi < 4; mi++)
#pragma unroll
        for (int ni = 0; ni < 4; ni++) {
            int col = bn + wn + ni * 16 + l15;
            float bv = bias[col];
#pragma unroll
            for (int r = 0; r < 4; r++) {
                int row = bm + wm + mi * 16 + l16 * 4 + r;
                float v = acc[mi][ni][r] + bv;
                if (RELU) v = fmaxf(v, 0.0f);
                Cout[(size_t)row * N + col] = f2bf(v);
            }
        }
}

// ---------------------------------------------------------------------------
// Fused GEMM (N=256) + bias (+bf16 residual) + LayerNorm (+PE | *mask).
// 128x256 tile, 512 threads = 8 waves. Output row remap: orow = ob + bb*ostr + sr.
template <int ADDLN>
__global__ __launch_bounds__(512) void gemm_ln_kernel(
    const u16* __restrict__ A, const u16* __restrict__ W,
    const float* __restrict__ bias, const u16* __restrict__ res,
    const float* __restrict__ pe,
    const float* __restrict__ g, const float* __restrict__ b2,
    const int* __restrict__ lengths, int len_add, int S,
    u16* __restrict__ outbf, int ob, int ostr, int M, int K)
{
    __shared__ u16 As[2][128 * 32];
    __shared__ u16 Bs[2][256 * 32];
    __shared__ float2 red[4][128];
    __shared__ float2 red2[128];
    const int bm = blockIdx.x * 128;
    const int tid = threadIdx.x;
    const int w = tid >> 6, lane = tid & 63;
    const int wm = (w >> 2) * 64, wc = w & 3, wn = wc * 64;
    const int l15 = lane & 15, l16 = lane >> 4;
    const int srow = lane >> 2, scol = (lane & 3) * 8;
    f32x4 acc[4][4] = {};

    const u16* ga0 = A + (size_t)(bm + 16 * w + srow) * K + scol;
    const u16* gb0 = W + (size_t)(16 * w + srow) * K + scol;
    const u16* gb1 = W + (size_t)(128 + 16 * w + srow) * K + scol;

#define STAGE_L(buf, kk)                                      \
    do {                                                      \
        gload16(ga0 + (kk), &As[buf][16 * w * 32]);           \
        gload16(gb0 + (kk), &Bs[buf][16 * w * 32]);           \
        gload16(gb1 + (kk), &Bs[buf][(128 + 16 * w) * 32]);   \
    } while (0)

    STAGE_L(0, 0);
    __syncthreads();
    int cur = 0;
    for (int k0 = 0; k0 < K; k0 += 32) {
        if (k0 + 32 < K) STAGE_L(cur ^ 1, k0 + 32);
        s16x8 af[4], bfr[4];
#pragma unroll
        for (int i = 0; i < 4; i++)
            af[i] = *(const s16x8*)&As[cur][(wm + i * 16 + l15) * 32 + l16 * 8];
#pragma unroll
        for (int i = 0; i < 4; i++)
            bfr[i] = *(const s16x8*)&Bs[cur][(wn + i * 16 + l15) * 32 + l16 * 8];
#pragma unroll
        for (int mi = 0; mi < 4; mi++)
#pragma unroll
            for (int ni = 0; ni < 4; ni++)
                acc[mi][ni] = __builtin_amdgcn_mfma_f32_16x16x32_bf16(af[mi], bfr[ni], acc[mi][ni], 0, 0, 0);
        __syncthreads();
        cur ^= 1;
    }
#undef STAGE_L

    float bcol[4];
#pragma unroll
    for (int ni = 0; ni < 4; ni++) bcol[ni] = bias[wn + ni * 16 + l15];
#pragma unroll
    for (int mi = 0; mi < 4; mi++)
#pragma unroll
        for (int ni = 0; ni < 4; ni++)
#pragma unroll
            for (int r = 0; r < 4; r++) {
                float v = acc[mi][ni][r] + bcol[ni];
                if (ADDLN)
                    v += bf2f(res[(size_t)(bm + wm + mi * 16 + l16 * 4 + r) * 256 + wn + ni * 16 + l15]);
                acc[mi][ni][r] = v;
            }
#pragma unroll
    for (int mi = 0; mi < 4; mi++)
#pragma unroll
        for (int r = 0; r < 4; r++) {
            float s = 0.0f, q = 0.0f;
#pragma unroll
            for (int ni = 0; ni < 4; ni++) { float v = acc[mi][ni][r]; s += v; q += v * v; }
#pragma unroll
            for (int off = 1; off <= 8; off <<= 1) {
                s += __shfl_xor(s, off, 64);
                q += __shfl_xor(q, off, 64);
            }
            if (l15 == 0) {
                float2 p; p.x = s; p.y = q;
                red[wc][wm + mi * 16 + l16 * 4 + r] = p;
            }
        }
    __syncthreads();
    if (tid < 128) {
        float s = 0.0f, q = 0.0f;
#pragma unroll
        for (int c = 0; c < 4; c++) { float2 p = red[c][tid]; s += p.x; q += p.y; }
        float mean = s * (1.0f / 256.0f);
        float var = q * (1.0f / 256.0f) - mean * mean;
        float2 o; o.x = mean; o.y = rsqrtf(var + 1e-5f);
        red2[tid] = o;
    }
    __syncthreads();
#pragma unroll
    for (int mi = 0; mi < 4; mi++)
#pragma unroll
        for (int r = 0; r < 4; r++) {
            int lrow = wm + mi * 16 + l16 * 4 + r;
            int grow = bm + lrow;
            float2 mr = red2[lrow];
            int bb = grow / S, sr = grow - bb * S;
            float mask = 1.0f;
            if (ADDLN) mask = (sr < lengths[bb] + len_add) ? 1.0f : 0.0f;
            size_t orow = (size_t)ob + (size_t)bb * ostr + sr;
#pragma unroll
            for (int ni = 0; ni < 4; ni++) {
                int col = wn + ni * 16 + l15;
                float o = (acc[mi][ni][r] - mr.x) * mr.y * g[col] + b2[col];
                if (ADDLN) o *= mask;
                else       o += pe[sr * 256 + col];
                outbf[orow * 256 + col] = f2bf(o);
            }
        }
}

// ---------------------------------------------------------------------------
// MFMA flash attention. One block per (b,h), 256 threads (4 waves).
// q-tiles fully beyond len skipped (rows >= len LN-masked to 0 downstream).
__global__ __launch_bounds__(256) void attn_mfma_kernel(
    const u16* __restrict__ qkv, u16* __restrict__ ctx,
    const int* __restrict__ lengths, int len_add, int S)
{
    __shared__ u16 K_lds[160][40];
    __shared__ u16 Vt_lds[32][176];
    __shared__ u16 P_lds[4][16][48];

    const int bh = blockIdx.x;
    const int b = bh >> 3, h = bh & 7;
    const int len = lengths[b] + len_add;
    const int tid = threadIdx.x;
    const int w = tid >> 6;
    const int lane = tid & 63;
    const int l15 = lane & 15, l16 = lane >> 4;
    const int SR = (S + 31) & ~31;   // staged rows (128 text, 160 fusion)

    const u16* kbase = qkv + ((size_t)b * S) * 768 + 256 + h * 32;
    const u16* vbase = kbase + 256;
    for (int chunk = tid; chunk < SR * 4; chunk += 256) {
        int s = chunk >> 2, d8 = (chunk & 3) * 8;
        u16x8 kv = {}; u16x8 vv = {};
        if (s < S) {
            kv = *(const u16x8*)(kbase + (size_t)s * 768 + d8);
            vv = *(const u16x8*)(vbase + (size_t)s * 768 + d8);
        }
        *(u16x8*)&K_lds[s][d8] = kv;
#pragma unroll
        for (int j = 0; j < 8; j++) Vt_lds[d8 + j][s] = vv[j];
    }
    __syncthreads();

    const f32x4 zero4 = {0.0f, 0.0f, 0.0f, 0.0f};
    const float SCALE = 0.17677669529663687f;

    for (int q0 = w * 16; q0 < len; q0 += 64) {
        const int qr = min(q0 + l15, S - 1);
        s16x8 qf = *(const s16x8*)(qkv + ((size_t)(b * S + qr)) * 768 + h * 32 + l16 * 8);
        f32x4 o0 = zero4, o1 = zero4;
        float mreg = -1e30f, lreg = 0.0f;

        for (int k0 = 0; k0 < len; k0 += 32) {
            s16x8 kf0 = *(const s16x8*)&K_lds[k0 + l15][l16 * 8];
            s16x8 kf1 = *(const s16x8*)&K_lds[k0 + 16 + l15][l16 * 8];
            __builtin_amdgcn_s_setprio(1);
            f32x4 c0 = __builtin_amdgcn_mfma_f32_16x16x32_bf16(kf0, qf, zero4, 0, 0, 0);
            f32x4 c1 = __builtin_amdgcn_mfma_f32_16x16x32_bf16(kf1, qf, zero4, 0, 0, 0);
            __builtin_amdgcn_s_setprio(0);
            float sc[8];
#pragma unroll
            for (int r = 0; r < 4; r++) {
                int key0 = k0 + l16 * 4 + r;
                sc[r]     = (key0 < len)      ? c0[r] * SCALE : -1e30f;
                sc[4 + r] = (key0 + 16 < len) ? c1[r] * SCALE : -1e30f;
            }
            float tmax = sc[0];
#pragma unroll
            for (int i = 1; i < 8; i++) tmax = fmaxf(tmax, sc[i]);
            tmax = fmaxf(tmax, __shfl_xor(tmax, 16, 64));
            tmax = fmaxf(tmax, __shfl_xor(tmax, 32, 64));
            float mnew = fmaxf(mreg, tmax);
            float rescale = expf(mreg - mnew);
            float psum = 0.0f;
            u16 pb[8];
#pragma unroll
            for (int i = 0; i < 8; i++) {
                float p = expf(sc[i] - mnew);
                psum += p;
                pb[i] = f2bf(p);
            }
            psum += __shfl_xor(psum, 16, 64);
            psum += __shfl_xor(psum, 32, 64);
            lreg = lreg * rescale + psum;
            mreg = mnew;
#pragma unroll
            for (int i = 0; i < 4; i++) { o0[i] *= rescale; o1[i] *= rescale; }
#pragma unroll
            for (int r = 0; r < 4; r++) {
                P_lds[w][l15][l16 * 4 + r]      = pb[r];
                P_lds[w][l15][16 + l16 * 4 + r] = pb[4 + r];
            }
            s16x8 pf  = *(const s16x8*)&P_lds[w][l15][l16 * 8];
            s16x8 vf0 = *(const s16x8*)&Vt_lds[l15][k0 + l16 * 8];
            s16x8 vf1 = *(const s16x8*)&Vt_lds[16 + l15][k0 + l16 * 8];
            __builtin_amdgcn_s_setprio(1);
            o0 = __builtin_amdgcn_mfma_f32_16x16x32_bf16(vf0, pf, o0, 0, 0, 0);
            o1 = __builtin_amdgcn_mfma_f32_16x16x32_bf16(vf1, pf, o1, 0, 0, 0);
            __builtin_amdgcn_s_setprio(0);
        }

        float inv = 1.0f / lreg;
        int qg = q0 + l15;
        if (qg < S) {
            size_t ob = ((size_t)(b * S + qg)) * 256 + h * 32;
#pragma unroll
            for (int r = 0; r < 4; r++) {
                ctx[ob + l16 * 4 + r]      = f2bf(o0[r] * inv);
                ctx[ob + 16 + l16 * 4 + r] = f2bf(o1[r] * inv);
            }
        }
    }
}

// ---------------------------------------------------------------------------
__global__ __launch_bounds__(64) void classifier_kernel(
    const u16* __restrict__ encFb, const float* __restrict__ age, const float* __restrict__ gen,
    const float* __restrict__ fc1_W, const float* __restrict__ fc1_b,
    const float* __restrict__ bn_g, const float* __restrict__ bn_b,
    const float* __restrict__ fc2_W, const float* __restrict__ fc2_b,
    float* __restrict__ outp)
{
    int k = blockIdx.x, b = blockIdx.y, t = threadIdx.x;
    const u16* cls = encFb + (size_t)b * SEQ_F * 256;
    const float* wrow = fc1_W + ((size_t)k * 64 + t) * 258;
    float acc = fc1_b[k * 64 + t];
    for (int d2 = 0; d2 < 256; d2++) acc += bf2f(cls[d2]) * wrow[d2];
    acc += age[b] * wrow[256] + gen[b] * wrow[257];
    const float RSQ = 0.99999500003749980e0f;
    acc = acc * RSQ * bn_g[k * 64 + t] + bn_b[k * 64 + t];
    acc = fmaxf(acc, 0.0f);
    float p = acc * fc2_W[k * 64 + t];
#pragma unroll
    for (int o = 32; o >= 1; o >>= 1) p += __shfl_xor(p, o, 64);
    if (t == 0) outp[k * 256 + b] = 1.0f / (1.0f + expf(-(p + fc2_b[k])));
}

// ---------------------------------------------------------------------------
struct WB { const u16 *inW, *attnW, *ff1W, *ff2W; };

static void run_encoder(u16* enc_bf, const u16* a_in, u16* ctx_buf, u16* scr_b,
                        const WB& wb, const float* pe, int S,
                        const float* in_b, const float* attn_b,
                        const float* ff_b1, const float* ff_b2,
                        const float* ln_g, const float* ln_b,
                        const int* lengths, int len_add,
                        u16* fout, int fbase, int fstr, hipStream_t stream)
{
    int M = BB * S;
    int MB = M / 128;
    dim3 g512(512 / 256, MB), g768(768 / 256, MB);
    gemm_ln_kernel<0><<<MB, 512, 0, stream>>>(a_in, wb.inW, in_b, nullptr, pe,
                                              ln_g, ln_b, lengths, len_add, S,
                                              enc_bf, 0, S, M, 256);
    for (int l = 0; l < NLAY; l++) {
        const u16* wqkv = wb.attnW + (size_t)l * 4 * 65536;
        const u16* wout = wb.attnW + ((size_t)l * 4 + 3) * 65536;
        const float* bqkv = attn_b + (size_t)l * 4 * 256;
        const float* bout = attn_b + ((size_t)l * 4 + 3) * 256;
        gemm_wide_kernel<0><<<g768, 512, 0, stream>>>(enc_bf, wqkv, bqkv, scr_b, M, 768, 256);
        attn_mfma_kernel<<<BB * NH, 256, 0, stream>>>(scr_b, ctx_buf, lengths, len_add, S);
        gemm_ln_kernel<1><<<MB, 512, 0, stream>>>(ctx_buf, wout, bout, enc_bf, nullptr,
                                                  ln_g + (1 + 2 * l) * 256, ln_b + (1 + 2 * l) * 256,
                                                  lengths, len_add, S, enc_bf, 0, S, M, 256);
        gemm_wide_kernel<1><<<g512, 512, 0, stream>>>(enc_bf, wb.ff1W + (size_t)l * 512 * 256,
                                                      ff_b1 + l * 512, scr_b, M, 512, 256);
        // final sublayer may redirect its output (fusion-seq write-through)
        u16* ob = (l == NLAY - 1) ? fout : enc_bf;
        int obase = (l == NLAY - 1) ? fbase : 0;
        int ostr  = (l == NLAY - 1) ? fstr : S;
        gemm_ln_kernel<1><<<MB, 512, 0, stream>>>(scr_b, wb.ff2W + (size_t)l * 256 * 512,
                                                  ff_b2 + l * 256, enc_bf, nullptr,
                                                  ln_g + (2 + 2 * l) * 256, ln_b + (2 + 2 * l) * 256,
                                                  lengths, len_add, S, ob, obase, ostr, M, 512);
    }
}

// ---------------------------------------------------------------------------
extern "C" void kernel_launch(void* const* d_in, const int* in_sizes, int n_in,
                              void* d_out, int out_size, void* d_ws, size_t ws_size,
                              hipStream_t stream)
{
    const float* x        = (const float*)d_in[0];
    const float* h0       = (const float*)d_in[1];
    const float* m        = (const float*)d_in[2];
    const float* dd       = (const float*)d_in[3];
    const float* x_m      = (const float*)d_in[4];
    const float* age      = (const float*)d_in[5];
    const float* gen      = (const float*)d_in[6];
    const int*   txts     = (const int*)d_in[8];
    const int*   txt_len  = (const int*)d_in[9];
    const float* dec_w    = (const float*)d_in[10];
    const float* dec_b    = (const float*)d_in[11];
    const float* hd_W     = (const float*)d_in[12];
    const float* hd_b     = (const float*)d_in[13];
    const float* gru_Wih  = (const float*)d_in[14];
    const float* gru_Whh  = (const float*)d_in[15];
    const float* gru_bih  = (const float*)d_in[16];
    const float* gru_bhh  = (const float*)d_in[17];
    const float* txt_emb  = (const float*)d_in[18];
    const float* t_in_W   = (const float*)d_in[19];
    const float* t_in_b   = (const float*)d_in[20];
    const float* t_attn_W = (const float*)d_in[21];
    const float* t_attn_b = (const float*)d_in[22];
    const float* t_ff_W1  = (const float*)d_in[23];
    const float* t_ff_b1  = (const float*)d_in[24];
    const float* t_ff_W2  = (const float*)d_in[25];
    const float* t_ff_b2  = (const float*)d_in[26];
    const float* t_ln_g   = (const float*)d_in[27];
    const float* t_ln_b   = (const float*)d_in[28];
    const float* f_in_W   = (const float*)d_in[29];
    const float* f_in_b   = (const float*)d_in[30];
    const float* f_attn_W = (const float*)d_in[31];
    const float* f_attn_b = (const float*)d_in[32];
    const float* f_ff_W1  = (const float*)d_in[33];
    const float* f_ff_b1  = (const float*)d_in[34];
    const float* f_ff_W2  = (const float*)d_in[35];
    const float* f_ff_b2  = (const float*)d_in[36];
    const float* f_ln_g   = (const float*)d_in[37];
    const float* f_ln_b   = (const float*)d_in[38];
    const float* f_cls    = (const float*)d_in[39];
    const float* fc1_W    = (const float*)d_in[40];
    const float* fc1_b    = (const float*)d_in[41];
    const float* bn_g     = (const float*)d_in[42];
    const float* bn_b     = (const float*)d_in[43];
    const float* fc2_W    = (const float*)d_in[44];
    const float* fc2_b    = (const float*)d_in[45];
    float* outp = (float*)d_out;

    // Workspace layout (float units; bf16 regions use half)
    const size_t O_PE    = 0;                        // 40960
    const size_t O_WHHT  = 40960;                    // whhT2 fp16 (98304 u16)
    const size_t O_ENCT  = 1810432;                  // encTb (8388608 u16) + text ctx (8388608 u16)
    const size_t O_ENCF  = 10199040;                 // encF bf16
    const size_t O_SCR   = 20226048;                 // gather-in / qkv/ff1 bf16
    const size_t O_ACTX  = 35266560;                 // fusion seq / fusion ctx
    const size_t O_WBF   = 50307072;                 // weights bf16
    const size_t TOTALF  = 51421184;                 // ~205.7 MB

    if (ws_size < TOTALF * sizeof(float)) {
        fprintf(stderr, "kernel_launch: ws_size %zu < required %zu bytes\n",
                ws_size, TOTALF * sizeof(float));
        return;
    }
    float* ws    = (float*)d_ws;
    float* pe    = ws + O_PE;
    u16*   whhT2 = (u16*)(ws + O_WHHT);
    u16*   encTb = (u16*)(ws + O_ENCT);
    u16*   ctxT  = encTb + (size_t)BB * SEQ_T * 256;   // back half of encT region
    u16*   encFb = (u16*)(ws + O_ENCF);
    u16*   scr_b = (u16*)(ws + O_SCR);
    u16*   actx_b= (u16*)(ws + O_ACTX);
    u16*   wbf   = (u16*)(ws + O_WBF);

    const size_t PER_ENC = PER_ENC_CAST;
    WB wbT = { wbf + 0,       wbf + 65536,           wbf + 589824,           wbf + 851968 };
    WB wbF = { wbf + PER_ENC, wbf + PER_ENC + 65536, wbf + PER_ENC + 589824, wbf + PER_ENC + 851968 };

    // Prep: weight casts + PE + packed fp16 Whh + txt gather (-> scr_b)
    prep_kernel<<<3097 + BB * SEQ_T, 256, 0, stream>>>(
        t_in_W, t_attn_W, t_ff_W1, t_ff_W2,
        f_in_W, f_attn_W, f_ff_W1, f_ff_W2,
        wbf, pe, gru_Whh, whhT2, txts, txt_emb, scr_b);

    // GRU-D scan -> bf16 emb rows written directly into fusion seq (actx_b)
    grud_kernel<<<BB, 768, 0, stream>>>(x, h0, m, dd, x_m, dec_w, dec_b, hd_W, hd_b,
                                        gru_Wih, gru_bih, whhT2, gru_bhh, actx_b);
    build_cls_kernel<<<BB, 256, 0, stream>>>(f_cls, actx_b);

    // Text encoder: A = gather (scr_b), ctx = ctxT (so fusion seq stays intact);
    // final ff2-LN writes DIRECTLY into fusion seq rows (b*153+25+s)
    run_encoder(encTb, scr_b, ctxT, scr_b, wbT, pe, SEQ_T,
                t_in_b, t_attn_b, t_ff_b1, t_ff_b2, t_ln_g, t_ln_b, txt_len, 0,
                actx_b, 25, SEQ_F, stream);

    // Fusion encoder: A = seq (actx_b), ctx = actx_b (seq dead after in-proj)
    run_encoder(encFb, actx_b, actx_b, scr_b, wbF, pe, SEQ_F,
                f_in_b, f_attn_b, f_ff_b1, f_ff_b2, f_ln_g, f_ln_b, txt_len, 25,
                encFb, 0, SEQ_F, stream);

    classifier_kernel<<<dim3(12, BB), 64, 0, stream>>>(encFb, age, gen, fc1_W, fc1_b,
                                                       bn_g, bn_b, fc2_W, fc2_b, outp);
}